// Round 1
// baseline (541.579 us; speedup 1.0000x reference)
//
#include <hip/hip_runtime.h>

// FocalCTCLoss on MI355X.
// B=256 batch, T=1024 timesteps, V=128 classes (BLANK=127), L=64 labels,
// S=2L+1=129 extended states.
//
// Mapping: one 64-lane wave per batch element (grid=256, block=64).
// Lane i owns extended states s=2i (blank) and s=2i+1 (label i); state 128
// (final blank) rides along in a third register (valid on lane 63).
// Wave-synchronous: no __syncthreads anywhere -> global prefetch loads stay
// in flight across DP iterations (fine-grained vmcnt from the compiler).

#define EPSF 1e-7f
#define NEG_INF -1e30f

constexpr int Bb = 256;
constexpr int Tt = 1024;
constexpr int Vv = 128;
constexpr int Ll = 64;

__device__ __forceinline__ float lse2(float a, float b) {
    // log(exp(a)+exp(b)), stable; exact-enough match to reference's 3-term
    // form (the dropped term is exp(NEG_INF - m) = 0).
    float m = fmaxf(a, b);
    float d = -fabsf(a - b);
    return m + __logf(1.0f + __expf(d));
}

__device__ __forceinline__ float lse3(float a, float b, float c) {
    float m = fmaxf(fmaxf(a, b), c);
    float s = __expf(a - m) + __expf(b - m) + __expf(c - m);
    return m + __logf(s);
}

__launch_bounds__(64, 1)
__global__ void ctc_dp_kernel(const int* __restrict__ y_true,
                              const float* __restrict__ y_pred,
                              float* __restrict__ focal_ws) {
    const int b    = blockIdx.x;
    const int lane = threadIdx.x;  // 0..63

    // Label owned by this lane (odd state 2*lane+1). Labels are in [0, V-2],
    // so never BLANK.
    const int lab      = y_true[b * Ll + lane];
    const int lab_prev = __shfl_up(lab, 1);
    // skip transition allowed for odd state iff label differs from label two
    // states back (lane 0: ext[-1]=BLANK -> allowed, but a2=NEG_INF anyway).
    const bool allow   = (lane == 0) || (lab != lab_prev);
    const int  lab_src = lab >> 1;   // lane holding p[lab] in its float2
    const bool lab_odd = (lab & 1) != 0;

    // Row base: lane i loads p[2i], p[2i+1] as one float2 (coalesced 512B/wave)
    const float2* row = (const float2*)(y_pred + (size_t)b * Tt * Vv) + lane;
    constexpr int ROWF2 = Vv / 2;  // 64 float2 per timestep

    // Software-pipelined prefetch, depth 8 (8 float2 = 16 VGPRs in flight).
    constexpr int PD = 8;
    float2 buf[PD];
#pragma unroll
    for (int d = 0; d < PD; ++d) buf[d] = row[d * ROWF2];

    // Pre-t0 state chosen so the generic step at t=0 yields the reference
    // alpha0: alpha0[0]=lp[0], alpha0[1]=lp[1], rest NEG_INF.
    float a_even = (lane == 0) ? 0.0f : NEG_INF;  // state 2*lane
    float a_odd  = NEG_INF;                       // state 2*lane+1
    float a128   = NEG_INF;                       // state 128 (lane 63)

    for (int tb = 0; tb < Tt; tb += PD) {
#pragma unroll
        for (int j = 0; j < PD; ++j) {
            const float2 v = buf[j];
            const int tn = tb + j + PD;
            if (tn < Tt) buf[j] = row[tn * ROWF2];

            // ---- per-timestep log-probs (off the recursion critical path)
            // denom = sum_v(p_v) + V*eps ; butterfly reduce over the wave
            float s = v.x + v.y;
#pragma unroll
            for (int off = 32; off > 0; off >>= 1) s += __shfl_xor(s, off);
            const float ld = __logf(s + (float)Vv * EPSF);

            const float pb       = __shfl(v.y, 63);        // p[127] = blank
            const float lp_blank = __logf(pb + EPSF) - ld;

            const float gx = __shfl(v.x, lab_src);
            const float gy = __shfl(v.y, lab_src);
            const float pl = lab_odd ? gy : gx;            // p[lab]
            const float lp_lab = __logf(pl + EPSF) - ld;

            // ---- alpha update (all from OLD values)
            float am1 = __shfl_up(a_odd, 1);               // alpha[2i-1]
            am1 = (lane == 0) ? NEG_INF : am1;

            // even state 2i (blank): no skip transition
            const float ne = lse2(a_even, am1) + lp_blank;
            // odd state 2i+1: self, from-blank, skip (if allowed)
            const float no =
                lse3(a_odd, a_even, allow ? am1 : NEG_INF) + lp_lab;
            // state 128: self + alpha[127] (lane 63's a_odd); computed on all
            // lanes (uniform instrs), only lane 63's value is meaningful.
            const float n128 = lse2(a128, a_odd) + lp_blank;

            a_even = ne;
            a_odd  = no;
            a128   = n128;
        }
    }

    if (lane == 63) {
        const float log_lik = lse2(a128, a_odd);  // LSE(alpha[128], alpha[127])
        const float loss    = -log_lik;
        const float p       = __expf(log_lik);
        const float om      = 1.0f - p;
        focal_ws[b] = 0.25f * om * om * loss;     // ALPHA*(1-p)^GAMMA*loss
    }
}

__global__ void finalize_kernel(const float* __restrict__ focal_ws,
                                float* __restrict__ out) {
    const int lane = threadIdx.x;  // 64 threads
    float s = 0.0f;
#pragma unroll
    for (int i = 0; i < Bb / 64; ++i) s += focal_ws[lane + 64 * i];
#pragma unroll
    for (int off = 32; off > 0; off >>= 1) s += __shfl_xor(s, off);
    if (lane == 0) out[0] = s * (1.0f / (float)Bb);
}

extern "C" void kernel_launch(void* const* d_in, const int* in_sizes, int n_in,
                              void* d_out, int out_size, void* d_ws, size_t ws_size,
                              hipStream_t stream) {
    const int*   y_true = (const int*)d_in[0];    // [B, L] int32
    const float* y_pred = (const float*)d_in[1];  // [B, T, V] float32
    float* focal_ws = (float*)d_ws;               // B floats of scratch

    ctc_dp_kernel<<<Bb, 64, 0, stream>>>(y_true, y_pred, focal_ws);
    finalize_kernel<<<1, 64, 0, stream>>>(focal_ws, (float*)d_out);
}

// Round 2
// 262.158 us; speedup vs baseline: 2.0659x; 2.0659x over previous
//
#include <hip/hip_runtime.h>

// FocalCTCLoss on MI355X — round 2.
// B=256, T=1024, V=128 (BLANK=127), L=64, S=129.
// One 64-lane wave per batch element; lane i owns states 2i, 2i+1; state 128
// rides in a 3rd register (valid lane 63).
//
// Round-1 post-mortem: 947 cy/iter, dominated by 9 serially-dependent DS ops
// (__shfl -> ds_bpermute) per iteration with only 1 wave resident.
// Fix: (a) linear-domain DP (softmax denom factors out; no exp/log in the
// recursion; exact power-of-2 rescale every 4 steps), (b) all cross-lane via
// DPP (VALU) — zero DS ops in the loop, (c) q[lab] via prefetched global
// gather (L1-hit, same lines as the row load).

#define EPSF 1e-7f

constexpr int Bb = 256;
constexpr int Tt = 1024;
constexpr int Vv = 128;
constexpr int Ll = 64;

// ---- DPP helpers (all VALU; ctrl codes per gfx9/CDNA DPP) ----------------
// 0x111..0x118 row_shr:1/2/4/8, 0x138 wave_shr:1, 0x142/0x143 row_bcast15/31
template <int Ctrl, int RowMask, int BankMask, bool BoundCtrl>
__device__ __forceinline__ float dppf(float x) {
    return __int_as_float(__builtin_amdgcn_update_dpp(
        0, __float_as_int(x), Ctrl, RowMask, BankMask, BoundCtrl));
}

// Wave-64 sum, result valid on lane 63. bound_ctrl=1 zero-fills shifted-in
// lanes (values are >= 0 here, and 0 is the sum identity).
__device__ __forceinline__ float wave_sum63(float x) {
    x += dppf<0x111, 0xf, 0xf, true>(x);
    x += dppf<0x112, 0xf, 0xf, true>(x);
    x += dppf<0x114, 0xf, 0xf, true>(x);
    x += dppf<0x118, 0xf, 0xf, true>(x);
    x += dppf<0x142, 0xa, 0xf, false>(x);  // row_bcast15 into rows 1,3
    x += dppf<0x143, 0xc, 0xf, false>(x);  // row_bcast31 into rows 2,3
    return x;
}

// Wave-64 max (non-negative inputs; 0-fill is the identity), valid lane 63.
__device__ __forceinline__ float wave_max63(float x) {
    x = fmaxf(x, dppf<0x111, 0xf, 0xf, true>(x));
    x = fmaxf(x, dppf<0x112, 0xf, 0xf, true>(x));
    x = fmaxf(x, dppf<0x114, 0xf, 0xf, true>(x));
    x = fmaxf(x, dppf<0x118, 0xf, 0xf, true>(x));
    x = fmaxf(x, dppf<0x142, 0xa, 0xf, false>(x));
    x = fmaxf(x, dppf<0x143, 0xc, 0xf, false>(x));
    return x;
}

__device__ __forceinline__ float bcast63(float x) {
    return __int_as_float(__builtin_amdgcn_readlane(__float_as_int(x), 63));
}

__launch_bounds__(64, 1)
__global__ void ctc_dp_kernel(const int* __restrict__ y_true,
                              const float* __restrict__ y_pred,
                              float* __restrict__ focal_ws) {
    const int b    = blockIdx.x;
    const int lane = threadIdx.x;  // 0..63

    // Label for odd state 2*lane+1 (in [0, V-2], never BLANK).
    const int lab  = y_true[b * Ll + lane];
    const int labp = __shfl_up(lab, 1);  // one DS op at init only
    // Skip transition into odd state allowed iff label differs from label
    // two states back; lane 0's alpha[-1] is 0 anyway.
    const float maskf = (lane == 0 || lab != labp) ? 1.0f : 0.0f;

    const float* base = y_pred + (size_t)b * Tt * Vv;
    const float2* row = (const float2*)base + lane;  // row[t*64] = {u[2i],u[2i+1]}
    const float*  gq  = base + lab;                  // gq[t*128] = u[lab]
    constexpr int ROWF2 = Vv / 2;

    constexpr int PD = 16;  // prefetch depth: 16*512B = 8KB in flight / wave
    float2 br[PD];
    float  bg[PD];
#pragma unroll
    for (int d = 0; d < PD; ++d) {
        br[d] = row[d * ROWF2];
        bg[d] = gq[d * Vv];
    }

    // Pre-t0 state: generic step at t=0 reproduces reference alpha0
    // (unnormalized linear domain: alpha[-inf] -> 0).
    float a_even = (lane == 0) ? 1.0f : 0.0f;  // state 2i
    float a_odd  = 0.0f;                       // state 2i+1
    float a128   = 0.0f;                       // state 128 (lane 63)
    float acc_ld = 0.0f;  // lane 63: sum_t log2(S_t + V*eps)
    int   eacc   = 0;     // power-of-2 rescale exponent (wave-uniform)

    auto step = [&](float2 v, float ql, bool rescale) {
        // --- softmax denominator term (independent chain; only lane 63's
        // accumulation is meaningful)
        float s = wave_sum63(v.x + v.y);
        acc_ld += __log2f(s + (float)Vv * EPSF);

        // --- unnormalized class scores q = u + eps
        const float qb = bcast63(v.y) + EPSF;  // q[127] (blank), wave-uniform
        const float qe = ql + EPSF;            // q[lab]

        // --- linear-domain alpha update (all from OLD values)
        // am1 = alpha[2i-1]; wave_shr:1 with bound_ctrl=1 -> lane0 gets 0.
        const float am1 = dppf<0x138, 0xf, 0xf, true>(a_odd);
        const float ne   = (a_even + am1) * qb;
        const float no   = (a_odd + a_even + maskf * am1) * qe;
        const float n128 = (a128 + a_odd) * qb;  // meaningful on lane 63 only
        a_even = ne;
        a_odd  = no;
        a128   = n128;

        // --- exact power-of-2 rescale every 4 steps (worst-case shrink per
        // window: eps^4 ~ 2^-93, safely inside fp32 range)
        if (rescale) {
            float mm = fmaxf(fmaxf(a_even, a_odd), a128);
            mm = wave_max63(mm);
            const float    wmax = bcast63(mm);  // > 0 always
            const unsigned e    = __float_as_uint(wmax) >> 23;
            const float scale   = __uint_as_float((254u - e) << 23);  // 2^(127-e)
            eacc += (int)e - 127;
            a_even *= scale;
            a_odd  *= scale;
            a128   *= scale;
        }
    };

    // Main loop: prefetch always in range (tb <= Tt-2*PD at last prefetch).
    for (int tb = 0; tb < Tt - PD; tb += PD) {
#pragma unroll
        for (int j = 0; j < PD; ++j) {
            const float2 v  = br[j];
            const float  ql = bg[j];
            const int    tn = tb + j + PD;
            br[j] = row[tn * ROWF2];
            bg[j] = gq[tn * Vv];
            step(v, ql, (j & 3) == 3);
        }
    }
    // Final PD timesteps: no prefetch.
#pragma unroll
    for (int j = 0; j < PD; ++j) {
        step(br[j], bg[j], (j & 3) == 3);
    }

    if (lane == 63) {
        // log_lik (nat) = ln2 * (log2(a128+a127) + eacc - sum_t log2(S_t+V*eps))
        float tot = fmaxf(a128 + a_odd, 1e-37f);
        const float log2lik = __log2f(tot) + (float)eacc - acc_ld;
        const float ln_lik  = 0.69314718055994530942f * log2lik;
        const float loss    = -ln_lik;
        const float p       = __expf(ln_lik);
        const float om      = 1.0f - p;
        focal_ws[b] = 0.25f * om * om * loss;  // ALPHA*(1-p)^GAMMA*loss
    }
}

__global__ void finalize_kernel(const float* __restrict__ focal_ws,
                                float* __restrict__ out) {
    const int lane = threadIdx.x;  // 64 threads
    float s = 0.0f;
#pragma unroll
    for (int i = 0; i < Bb / 64; ++i) s += focal_ws[lane + 64 * i];
#pragma unroll
    for (int off = 32; off > 0; off >>= 1) s += __shfl_xor(s, off);
    if (lane == 0) out[0] = s * (1.0f / (float)Bb);
}

extern "C" void kernel_launch(void* const* d_in, const int* in_sizes, int n_in,
                              void* d_out, int out_size, void* d_ws, size_t ws_size,
                              hipStream_t stream) {
    const int*   y_true = (const int*)d_in[0];    // [B, L] int32
    const float* y_pred = (const float*)d_in[1];  // [B, T, V] float32
    float* focal_ws = (float*)d_ws;               // B floats of scratch

    ctc_dp_kernel<<<Bb, 64, 0, stream>>>(y_true, y_pred, focal_ws);
    finalize_kernel<<<1, 64, 0, stream>>>(focal_ws, (float*)d_out);
}

// Round 3
// 248.246 us; speedup vs baseline: 2.1816x; 1.0560x over previous
//
#include <hip/hip_runtime.h>

// FocalCTCLoss on MI355X — round 3.
// B=256, T=1024, V=128 (BLANK=127), L=64, S=129.
//
// Round-2 post-mortem: DP kernel latency-chain bound at 284 cy/iter with 1
// wave/CU; the per-step wave_sum63+log2 (softmax denominator) was the longest
// chain and is recursion-independent. Split:
//   1. denom_kernel — massively parallel, BW-bound: acc_ld[b] = sum_t log2(S_t+V*eps)
//   2. ctc_dp_kernel — only the sequential recursion: ~8 VALU/step, branchy
//      underflow-only rescale (values never grow: q <= 1+eps)
//   3. finalize_kernel — focal loss per b + mean

#define EPSF 1e-7f

constexpr int Bb = 256;
constexpr int Tt = 1024;
constexpr int Vv = 128;
constexpr int Ll = 64;

// ---- DPP helpers -----------------------------------------------------------
template <int Ctrl, int RowMask, int BankMask, bool BoundCtrl>
__device__ __forceinline__ float dppf(float x) {
    return __int_as_float(__builtin_amdgcn_update_dpp(
        0, __float_as_int(x), Ctrl, RowMask, BankMask, BoundCtrl));
}

// Wave-64 sum, valid on lane 63 (inputs >= 0; 0-fill is identity).
__device__ __forceinline__ float wave_sum63(float x) {
    x += dppf<0x111, 0xf, 0xf, true>(x);
    x += dppf<0x112, 0xf, 0xf, true>(x);
    x += dppf<0x114, 0xf, 0xf, true>(x);
    x += dppf<0x118, 0xf, 0xf, true>(x);
    x += dppf<0x142, 0xa, 0xf, false>(x);  // row_bcast15 -> rows 1,3
    x += dppf<0x143, 0xc, 0xf, false>(x);  // row_bcast31 -> rows 2,3
    return x;
}

// Wave-64 max (non-negative inputs), valid on lane 63.
__device__ __forceinline__ float wave_max63(float x) {
    x = fmaxf(x, dppf<0x111, 0xf, 0xf, true>(x));
    x = fmaxf(x, dppf<0x112, 0xf, 0xf, true>(x));
    x = fmaxf(x, dppf<0x114, 0xf, 0xf, true>(x));
    x = fmaxf(x, dppf<0x118, 0xf, 0xf, true>(x));
    x = fmaxf(x, dppf<0x142, 0xa, 0xf, false>(x));
    x = fmaxf(x, dppf<0x143, 0xc, 0xf, false>(x));
    return x;
}

__device__ __forceinline__ float bcast63(float x) {
    return __int_as_float(__builtin_amdgcn_readlane(__float_as_int(x), 63));
}

// ---- 1. softmax-denominator pre-pass (BW-bound, fully parallel) ------------
// acc_ld[b] = sum_t log2( sum_v y_pred[b,t,v] + V*eps )
__launch_bounds__(1024, 1)
__global__ void denom_kernel(const float* __restrict__ y_pred,
                             float* __restrict__ acc_ld) {
    const int b    = blockIdx.x;
    const int lane = threadIdx.x & 63;
    const int wv   = threadIdx.x >> 6;  // 0..15
    const float2* base = (const float2*)(y_pred + (size_t)b * Tt * Vv);

    float ll = 0.0f;
    // wave wv handles rows t in {t0, t0+16, t0+32, t0+48} per outer iter;
    // 4 loads issued up-front for MLP (64 outstanding 512B loads per CU).
    for (int t0 = wv; t0 < Tt; t0 += 64) {
        float2 v0 = base[(t0 +  0) * 64 + lane];
        float2 v1 = base[(t0 + 16) * 64 + lane];
        float2 v2 = base[(t0 + 32) * 64 + lane];
        float2 v3 = base[(t0 + 48) * 64 + lane];
        float s0 = wave_sum63(v0.x + v0.y);
        float s1 = wave_sum63(v1.x + v1.y);
        float s2 = wave_sum63(v2.x + v2.y);
        float s3 = wave_sum63(v3.x + v3.y);
        // only lane 63's accumulation is meaningful
        ll += __log2f(s0 + (float)Vv * EPSF) + __log2f(s1 + (float)Vv * EPSF) +
              __log2f(s2 + (float)Vv * EPSF) + __log2f(s3 + (float)Vv * EPSF);
    }

    __shared__ float part[16];
    if (lane == 63) part[wv] = ll;
    __syncthreads();
    if (threadIdx.x == 0) {
        float t = 0.0f;
#pragma unroll
        for (int i = 0; i < 16; ++i) t += part[i];
        acc_ld[b] = t;
    }
}

// ---- 2. sequential CTC recursion (latency-bound; minimal chain) ------------
// dp_out[b] = log2( alpha_T[128] + alpha_T[127] ) + eacc   (unnormalized)
__launch_bounds__(64, 1)
__global__ void ctc_dp_kernel(const int* __restrict__ y_true,
                              const float* __restrict__ y_pred,
                              float* __restrict__ dp_out) {
    const int b    = blockIdx.x;
    const int lane = threadIdx.x;

    const int lab  = y_true[b * Ll + lane];       // label of odd state 2i+1
    const int labp = __shfl_up(lab, 1);
    const float maskf = (lane == 0 || lab != labp) ? 1.0f : 0.0f;

    const float* yb = y_pred + (size_t)b * Tt * Vv;  // uniform base

    constexpr int PD = 16;
    float bg[PD];   // u[t][lab]  (divergent gather, L3-warm)
    float bq[PD];   // u[t][127]  (uniform -> scalar loads)
#pragma unroll
    for (int d = 0; d < PD; ++d) {
        bg[d] = yb[d * Vv + lab];
        bq[d] = yb[d * Vv + 127];
    }

    // Pre-t0 state: generic step at t=0 reproduces reference alpha0.
    float a_even = (lane == 0) ? 1.0f : 0.0f;
    float a_odd  = 0.0f;
    float a128   = 0.0f;
    int   eacc   = 0;

    auto step = [&](float g, float qbl, bool check) {
        const float qe = g + EPSF;
        const float qb = qbl + EPSF;
        const float am1 = dppf<0x138, 0xf, 0xf, true>(a_odd);  // alpha[2i-1]
        const float ne   = (a_even + am1) * qb;
        const float no   = (a_odd + a_even + maskf * am1) * qe;
        const float n128 = (a128 + a_odd) * qb;   // meaningful lane 63 only
        a_even = ne;
        a_odd  = no;
        a128   = n128;
        if (check) {
            // Values only shrink (q <= 1+eps); rescale only on underflow risk.
            // Worst-case shrink per 4-step window is eps^4 ~ 2^-93, so a
            // 2^-25 trigger keeps everything in normal fp32 range.
            const float m = fmaxf(fmaxf(a_even, a_odd), a128);
            if (__all(m < 0x1p-25f)) {
                float mm = wave_max63(m);
                const float    wmax  = bcast63(mm);            // > 0 always
                const unsigned e     = __float_as_uint(wmax) >> 23;
                const float    scale = __uint_as_float((254u - e) << 23);
                eacc += (int)e - 127;
                a_even *= scale;
                a_odd  *= scale;
                a128   *= scale;
            }
        }
    };

    for (int tb = 0; tb < Tt - PD; tb += PD) {
#pragma unroll
        for (int j = 0; j < PD; ++j) {
            const float g  = bg[j];
            const float qb = bq[j];
            const int   tn = tb + j + PD;
            bg[j] = yb[tn * Vv + lab];
            bq[j] = yb[tn * Vv + 127];
            step(g, qb, (j & 3) == 3);
        }
    }
#pragma unroll
    for (int j = 0; j < PD; ++j) step(bg[j], bq[j], (j & 3) == 3);

    if (lane == 63) {
        const float tot = fmaxf(a128 + a_odd, 1e-37f);
        dp_out[b] = __log2f(tot) + (float)eacc;
    }
}

// ---- 3. focal loss + mean --------------------------------------------------
__global__ void finalize_kernel(const float* __restrict__ dp_out,
                                const float* __restrict__ acc_ld,
                                float* __restrict__ out) {
    const int i    = threadIdx.x;        // 256 threads = 4 waves
    const int lane = i & 63;
    const int wv   = i >> 6;

    const float log2lik = dp_out[i] - acc_ld[i];
    const float ln_lik  = 0.69314718055994530942f * log2lik;
    const float loss    = -ln_lik;
    const float p       = __expf(ln_lik);
    const float om      = 1.0f - p;
    float f = 0.25f * om * om * loss;

#pragma unroll
    for (int off = 32; off > 0; off >>= 1) f += __shfl_xor(f, off);

    __shared__ float red[4];
    if (lane == 0) red[wv] = f;
    __syncthreads();
    if (i == 0)
        out[0] = (red[0] + red[1] + red[2] + red[3]) * (1.0f / (float)Bb);
}

extern "C" void kernel_launch(void* const* d_in, const int* in_sizes, int n_in,
                              void* d_out, int out_size, void* d_ws, size_t ws_size,
                              hipStream_t stream) {
    const int*   y_true = (const int*)d_in[0];    // [B, L] int32
    const float* y_pred = (const float*)d_in[1];  // [B, T, V] float32
    float* dp_out = (float*)d_ws;                 // [B]
    float* acc_ld = (float*)d_ws + Bb;            // [B]

    denom_kernel<<<Bb, 1024, 0, stream>>>(y_pred, acc_ld);   // also warms L3
    ctc_dp_kernel<<<Bb, 64, 0, stream>>>(y_true, y_pred, dp_out);
    finalize_kernel<<<1, 256, 0, stream>>>(dp_out, acc_ld, (float*)d_out);
}

// Round 4
// 233.240 us; speedup vs baseline: 2.3220x; 1.0643x over previous
//
#include <hip/hip_runtime.h>

// FocalCTCLoss on MI355X — round 4.
// B=256, T=1024, V=128 (BLANK=127), L=64, S=129.
//
// Round-3 post-mortem: ~137 us of the timed window is harness reset traffic
// (512MB ws poison at 87% HBM peak + input restore) — untouchable. Our two
// kernels (denom ~, dp ~) ran serially though independent. Fix: fuse into one
// kernel, one 1024-thread block per batch element:
//   wave 0     : sequential CTC recursion (latency-chain, ~4 dep VALU/step)
//   waves 1-15 : softmax-denominator row sums (BW-bound float4 stream),
//                co-scheduled on the same CU's other SIMD slots
// One __syncthreads, lane 63 of wave 0 combines and writes focal_ws[b].

#define EPSF 1e-7f

constexpr int Bb = 256;
constexpr int Tt = 1024;
constexpr int Vv = 128;
constexpr int Ll = 64;

// ---- DPP helpers -----------------------------------------------------------
template <int Ctrl, int RowMask, int BankMask, bool BoundCtrl>
__device__ __forceinline__ float dppf(float x) {
    return __int_as_float(__builtin_amdgcn_update_dpp(
        0, __float_as_int(x), Ctrl, RowMask, BankMask, BoundCtrl));
}

// Wave-64 sum, valid on lane 63 (inputs >= 0; 0-fill is identity).
__device__ __forceinline__ float wave_sum63(float x) {
    x += dppf<0x111, 0xf, 0xf, true>(x);
    x += dppf<0x112, 0xf, 0xf, true>(x);
    x += dppf<0x114, 0xf, 0xf, true>(x);
    x += dppf<0x118, 0xf, 0xf, true>(x);
    x += dppf<0x142, 0xa, 0xf, false>(x);  // row_bcast15 -> rows 1,3
    x += dppf<0x143, 0xc, 0xf, false>(x);  // row_bcast31 -> rows 2,3
    return x;
}

// Half-wave sums: lane 31 = sum(lanes 0..31), lane 63 = sum(lanes 32..63).
__device__ __forceinline__ float half_sum(float x) {
    x += dppf<0x111, 0xf, 0xf, true>(x);
    x += dppf<0x112, 0xf, 0xf, true>(x);
    x += dppf<0x114, 0xf, 0xf, true>(x);
    x += dppf<0x118, 0xf, 0xf, true>(x);
    x += dppf<0x142, 0xa, 0xf, false>(x);  // row_bcast15 -> rows 1,3
    return x;
}

// Wave-64 max (non-negative inputs), valid on lane 63.
__device__ __forceinline__ float wave_max63(float x) {
    x = fmaxf(x, dppf<0x111, 0xf, 0xf, true>(x));
    x = fmaxf(x, dppf<0x112, 0xf, 0xf, true>(x));
    x = fmaxf(x, dppf<0x114, 0xf, 0xf, true>(x));
    x = fmaxf(x, dppf<0x118, 0xf, 0xf, true>(x));
    x = fmaxf(x, dppf<0x142, 0xa, 0xf, false>(x));
    x = fmaxf(x, dppf<0x143, 0xc, 0xf, false>(x));
    return x;
}

__device__ __forceinline__ float bcast63(float x) {
    return __int_as_float(__builtin_amdgcn_readlane(__float_as_int(x), 63));
}

// ---- fused kernel: one block per batch element -----------------------------
__launch_bounds__(1024, 1)
__global__ void fused_kernel(const int* __restrict__ y_true,
                             const float* __restrict__ y_pred,
                             float* __restrict__ focal_ws) {
    const int b    = blockIdx.x;
    const int lane = threadIdx.x & 63;
    const int wv   = threadIdx.x >> 6;  // 0..15

    const float* yb = y_pred + (size_t)b * Tt * Vv;

    __shared__ float part[30];  // 15 denom waves x 2 half-wave partials

    // DP results (wave 0, meaningful on lane 63)
    float a_odd = 0.0f, a128 = 0.0f;
    int   eacc  = 0;

    if (wv == 0) {
        // ---------------- sequential CTC recursion (latency-bound) ---------
        const int lab  = y_true[b * Ll + lane];   // label of odd state 2i+1
        const int labp = __shfl_up(lab, 1);
        const float maskf = (lane == 0 || lab != labp) ? 1.0f : 0.0f;

        constexpr int PD = 16;
        float bg[PD];   // u[t][lab]  (divergent gather within one 512B row)
        float bq[PD];   // u[t][127]  (uniform -> scalar loads)
#pragma unroll
        for (int d = 0; d < PD; ++d) {
            bg[d] = yb[d * Vv + lab];
            bq[d] = yb[d * Vv + 127];
        }

        // Pre-t0 state: generic step at t=0 reproduces reference alpha0.
        float a_even = (lane == 0) ? 1.0f : 0.0f;

        auto step = [&](float g, float qbl, bool check) {
            const float qe = g + EPSF;
            const float qb = qbl + EPSF;
            const float am1 = dppf<0x138, 0xf, 0xf, true>(a_odd);  // a[2i-1]
            const float ne   = (a_even + am1) * qb;
            const float no   = (a_odd + a_even + maskf * am1) * qe;
            const float n128 = (a128 + a_odd) * qb;  // lane 63 only
            a_even = ne;
            a_odd  = no;
            a128   = n128;
            if (check) {
                // Values only shrink (q <= 1+eps); rescale on underflow risk.
                const float m = fmaxf(fmaxf(a_even, a_odd), a128);
                if (__all(m < 0x1p-25f)) {
                    float mm = wave_max63(m);
                    const float    wmax  = bcast63(mm);           // > 0
                    const unsigned e     = __float_as_uint(wmax) >> 23;
                    const float    scale = __uint_as_float((254u - e) << 23);
                    eacc += (int)e - 127;
                    a_even *= scale;
                    a_odd  *= scale;
                    a128   *= scale;
                }
            }
        };

        for (int tb = 0; tb < Tt - PD; tb += PD) {
#pragma unroll
            for (int j = 0; j < PD; ++j) {
                const float g  = bg[j];
                const float q  = bq[j];
                const int   tn = tb + j + PD;
                bg[j] = yb[tn * Vv + lab];
                bq[j] = yb[tn * Vv + 127];
                step(g, q, (j & 3) == 3);
            }
        }
#pragma unroll
        for (int j = 0; j < PD; ++j) step(bg[j], bq[j], (j & 3) == 3);
    } else {
        // ---------------- softmax denominator (BW-bound) -------------------
        // Row-pair rp covers rows 2rp, 2rp+1 (1 KB): lanes 0-31 row 2rp,
        // lanes 32-63 row 2rp+1; one __log2f computes both rows' logs.
        const float4* b4 = (const float4*)yb;
        const int w  = wv - 1;                 // 0..14
        const int rs = (w * 512) / 15;         // contiguous chunk per wave
        const int re = ((w + 1) * 512) / 15;

        float ll = 0.0f;                       // lanes 31 & 63 meaningful
        int rp = rs;
        for (; rp + 2 <= re; rp += 2) {
            const float4 v0 = b4[rp * 64 + lane];
            const float4 v1 = b4[rp * 64 + 64 + lane];
            const float s0 = half_sum(v0.x + v0.y + v0.z + v0.w);
            const float s1 = half_sum(v1.x + v1.y + v1.z + v1.w);
            ll += __log2f(s0 + (float)Vv * EPSF) +
                  __log2f(s1 + (float)Vv * EPSF);
        }
        if (rp < re) {
            const float4 v0 = b4[rp * 64 + lane];
            const float s0 = half_sum(v0.x + v0.y + v0.z + v0.w);
            ll += __log2f(s0 + (float)Vv * EPSF);
        }
        if ((lane & 31) == 31) part[2 * w + (lane >> 5)] = ll;
    }

    __syncthreads();

    if (wv == 0) {
        float v = (lane < 30) ? part[lane] : 0.0f;
        v = wave_sum63(v);
        if (lane == 63) {
            const float acc_ld = v;  // sum_t log2(S_t + V*eps)
            const float tot    = fmaxf(a128 + a_odd, 1e-37f);
            const float log2lik = __log2f(tot) + (float)eacc - acc_ld;
            const float ln_lik  = 0.69314718055994530942f * log2lik;
            const float loss    = -ln_lik;
            const float p       = __expf(ln_lik);
            const float om      = 1.0f - p;
            focal_ws[b] = 0.25f * om * om * loss;
        }
    }
}

// ---- focal mean -------------------------------------------------------------
__global__ void finalize_kernel(const float* __restrict__ focal_ws,
                                float* __restrict__ out) {
    const int i    = threadIdx.x;  // 256 threads = 4 waves
    const int lane = i & 63;
    const int wv   = i >> 6;

    float f = focal_ws[i];
#pragma unroll
    for (int off = 32; off > 0; off >>= 1) f += __shfl_xor(f, off);

    __shared__ float red[4];
    if (lane == 0) red[wv] = f;
    __syncthreads();
    if (i == 0)
        out[0] = (red[0] + red[1] + red[2] + red[3]) * (1.0f / (float)Bb);
}

extern "C" void kernel_launch(void* const* d_in, const int* in_sizes, int n_in,
                              void* d_out, int out_size, void* d_ws, size_t ws_size,
                              hipStream_t stream) {
    const int*   y_true = (const int*)d_in[0];    // [B, L] int32
    const float* y_pred = (const float*)d_in[1];  // [B, T, V] float32
    float* focal_ws = (float*)d_ws;               // [B]

    fused_kernel<<<Bb, 1024, 0, stream>>>(y_true, y_pred, focal_ws);
    finalize_kernel<<<1, 256, 0, stream>>>(focal_ws, (float*)d_out);
}

// Round 5
// 202.296 us; speedup vs baseline: 2.6772x; 1.1530x over previous
//
#include <hip/hip_runtime.h>

// FocalCTCLoss on MI355X — round 5.
// B=256, T=1024, V=128 (BLANK=127), L=64, S=129.
//
// Round-4 post-mortem: fused kernel still 222 cy/DP-step. The uniform blank
// load compiled to s_load (SGPR_Count=80, VGPR=28); SMEM is out-of-order so
// each use forces lgkmcnt(0), draining the whole scalar prefetch queue —
// the register pipeline was structurally defeated. Gather loads also fought
// 15 streaming waves for HBM.
//
// Fix: producer-consumer via LDS. Waves 1-15 stream 128-timestep chunks
// (64 KB) into a double-buffered LDS tile + compacted blank[t] array (free:
// it's v.w of lanes 31/63), computing denom row-sum logs from the same
// registers. Wave 0 runs the recursion purely from LDS: in-order ds_read,
// fine-grained lgkmcnt, 8-deep register prefetch. Zero global/SMEM loads in
// the recursion. 9 __syncthreads total.

#define EPSF 1e-7f

constexpr int Bb  = 256;
constexpr int Tt  = 1024;
constexpr int Vv  = 128;
constexpr int Ll  = 64;
constexpr int CH  = 128;       // timesteps per chunk
constexpr int NCH = Tt / CH;   // 8 chunks
constexpr int PAIRS = CH / 2;  // 64 row-pairs per chunk

// ---- DPP helpers -----------------------------------------------------------
template <int Ctrl, int RowMask, int BankMask, bool BoundCtrl>
__device__ __forceinline__ float dppf(float x) {
    return __int_as_float(__builtin_amdgcn_update_dpp(
        0, __float_as_int(x), Ctrl, RowMask, BankMask, BoundCtrl));
}

// Wave-64 sum, valid on lane 63 (inputs >= 0; 0-fill is identity).
__device__ __forceinline__ float wave_sum63(float x) {
    x += dppf<0x111, 0xf, 0xf, true>(x);
    x += dppf<0x112, 0xf, 0xf, true>(x);
    x += dppf<0x114, 0xf, 0xf, true>(x);
    x += dppf<0x118, 0xf, 0xf, true>(x);
    x += dppf<0x142, 0xa, 0xf, false>(x);  // row_bcast15 -> rows 1,3
    x += dppf<0x143, 0xc, 0xf, false>(x);  // row_bcast31 -> rows 2,3
    return x;
}

// Half-wave sums: lane 31 = sum(lanes 0..31), lane 63 = sum(lanes 32..63).
__device__ __forceinline__ float half_sum(float x) {
    x += dppf<0x111, 0xf, 0xf, true>(x);
    x += dppf<0x112, 0xf, 0xf, true>(x);
    x += dppf<0x114, 0xf, 0xf, true>(x);
    x += dppf<0x118, 0xf, 0xf, true>(x);
    x += dppf<0x142, 0xa, 0xf, false>(x);
    return x;
}

// Wave-64 max (non-negative inputs), valid on lane 63.
__device__ __forceinline__ float wave_max63(float x) {
    x = fmaxf(x, dppf<0x111, 0xf, 0xf, true>(x));
    x = fmaxf(x, dppf<0x112, 0xf, 0xf, true>(x));
    x = fmaxf(x, dppf<0x114, 0xf, 0xf, true>(x));
    x = fmaxf(x, dppf<0x118, 0xf, 0xf, true>(x));
    x = fmaxf(x, dppf<0x142, 0xa, 0xf, false>(x));
    x = fmaxf(x, dppf<0x143, 0xc, 0xf, false>(x));
    return x;
}

__device__ __forceinline__ float bcast63(float x) {
    return __int_as_float(__builtin_amdgcn_readlane(__float_as_int(x), 63));
}

// ---- fused producer-consumer kernel: one block per batch element -----------
__launch_bounds__(1024, 1)
__global__ void fused_kernel(const int* __restrict__ y_true,
                             const float* __restrict__ y_pred,
                             float* __restrict__ focal_ws) {
    const int b    = blockIdx.x;
    const int lane = threadIdx.x & 63;
    const int wv   = threadIdx.x >> 6;  // 0..15

    const float*  yb  = y_pred + (size_t)b * Tt * Vv;
    const float4* yb4 = (const float4*)yb;

    // LDS: double-buffered chunk tile + compacted blank array + partials.
    __shared__ float4 l4buf[2 * CH * (Vv / 4)];  // 128 KB
    __shared__ float  lblk[2 * CH];              // 1 KB: u[t][127] per step
    __shared__ float  part[30];                  // 15 waves x 2 half partials
    float* lrows = (float*)l4buf;

    // ---- DP state (wave 0; meaningful on lane 63) --------------------------
    float a_even = 0.0f, a_odd = 0.0f, a128 = 0.0f;
    int   eacc = 0;
    float maskf = 0.0f;
    int   lab = 0;

    // ---- loader state (waves 1..15) ---------------------------------------
    const int w    = wv - 1;       // 0..14
    const int half = lane >> 5;    // 0: even row of pair, 1: odd row
    float ll = 0.0f;               // lanes 31/63: sum of log2 row-sums

    if (wv == 0) {
        lab = y_true[b * Ll + lane];           // label of odd state 2*lane+1
        const int labp = __shfl_up(lab, 1);
        maskf  = (lane == 0 || lab != labp) ? 1.0f : 0.0f;
        a_even = (lane == 0) ? 1.0f : 0.0f;    // pre-t0 init
    }

    auto step = [&](float g, float qbl, bool check) {
        const float qe  = g + EPSF;
        const float qb  = qbl + EPSF;
        const float am1 = dppf<0x138, 0xf, 0xf, true>(a_odd);  // alpha[2i-1]
        const float ne   = (a_even + am1) * qb;
        const float no   = (a_odd + a_even + maskf * am1) * qe;
        const float n128 = (a128 + a_odd) * qb;  // lane 63 only
        a_even = ne;
        a_odd  = no;
        a128   = n128;
        if (check) {
            // Values only shrink (q <= 1+eps); rescale on underflow risk only.
            const float m = fmaxf(fmaxf(a_even, a_odd), a128);
            if (__all(m < 0x1p-25f)) {
                float mm = wave_max63(m);
                const float    wmax  = bcast63(mm);            // > 0
                const unsigned e     = __float_as_uint(wmax) >> 23;
                const float    scale = __uint_as_float((254u - e) << 23);
                eacc += (int)e - 127;
                a_even *= scale;
                a_odd  *= scale;
                a128   *= scale;
            }
        }
    };

    for (int p = 0; p <= NCH; ++p) {
        if (wv != 0) {
            if (p < NCH) {
                // ------- produce chunk p into buffer (p&1) ------------------
                const int bsel  = p & 1;
                const int gbase = p * CH * (Vv / 4);    // global f4 offset
                const int lbase = bsel * CH * (Vv / 4); // LDS f4 offset
                // 5 row-pairs per wave, stride 15 (64 pairs; tail clamped).
                float4 v[5];
                int    rpc[5];
#pragma unroll
                for (int k = 0; k < 5; ++k) {
                    const int rp = w + 15 * k;          // 0..74
                    rpc[k] = rp < PAIRS ? rp : PAIRS - 1;
                    v[k]   = yb4[gbase + rpc[k] * 64 + lane];
                }
#pragma unroll
                for (int k = 0; k < 5; ++k) {
                    const bool valid = (w + 15 * k) < PAIRS;  // wave-uniform
                    if (valid) {
                        l4buf[lbase + rpc[k] * 64 + lane] = v[k];
                        const float s =
                            half_sum(v[k].x + v[k].y + v[k].z + v[k].w);
                        if ((lane & 31) == 31) {
                            // lane 31: row 2rp; lane 63: row 2rp+1.
                            // v.w of these lanes is u[row][127] = blank.
                            lblk[bsel * CH + 2 * rpc[k] + half] = v[k].w;
                            ll += __log2f(s + (float)Vv * EPSF);
                        }
                    }
                }
            } else if ((lane & 31) == 31) {
                part[2 * w + half] = ll;  // p == NCH: publish denom partials
            }
        } else if (p > 0) {
            // ------- consume chunk p-1 from buffer ((p-1)&1) ----------------
            const int bsel = (p - 1) & 1;
            const int cb   = bsel * CH * Vv;  // float offset of tile
            const int bb   = bsel * CH;
            constexpr int PD = 8;
            float gq[PD], bq[PD];
#pragma unroll
            for (int d = 0; d < PD; ++d) {
                gq[d] = lrows[cb + d * Vv + lab];  // divergent gather
                bq[d] = lblk[bb + d];              // uniform broadcast
            }
            for (int t0 = 0; t0 < CH - PD; t0 += PD) {
#pragma unroll
                for (int j = 0; j < PD; ++j) {
                    const float g = gq[j];
                    const float q = bq[j];
                    const int  tn = t0 + j + PD;
                    gq[j] = lrows[cb + tn * Vv + lab];
                    bq[j] = lblk[bb + tn];
                    step(g, q, (j & 3) == 3);
                }
            }
#pragma unroll
            for (int j = 0; j < PD; ++j) step(gq[j], bq[j], (j & 3) == 3);
        }
        __syncthreads();
    }

    if (wv == 0) {
        float vs = (lane < 30) ? part[lane] : 0.0f;
        vs = wave_sum63(vs);
        if (lane == 63) {
            const float acc_ld = vs;  // sum_t log2(S_t + V*eps)
            const float tot    = fmaxf(a128 + a_odd, 1e-37f);
            const float log2lik = __log2f(tot) + (float)eacc - acc_ld;
            const float ln_lik  = 0.69314718055994530942f * log2lik;
            const float loss    = -ln_lik;
            const float pp      = __expf(ln_lik);
            const float om      = 1.0f - pp;
            focal_ws[b] = 0.25f * om * om * loss;
        }
    }
}

// ---- focal mean -------------------------------------------------------------
__global__ void finalize_kernel(const float* __restrict__ focal_ws,
                                float* __restrict__ out) {
    const int i    = threadIdx.x;  // 256 threads = 4 waves
    const int lane = i & 63;
    const int wv   = i >> 6;

    float f = focal_ws[i];
#pragma unroll
    for (int off = 32; off > 0; off >>= 1) f += __shfl_xor(f, off);

    __shared__ float red[4];
    if (lane == 0) red[wv] = f;
    __syncthreads();
    if (i == 0)
        out[0] = (red[0] + red[1] + red[2] + red[3]) * (1.0f / (float)Bb);
}

extern "C" void kernel_launch(void* const* d_in, const int* in_sizes, int n_in,
                              void* d_out, int out_size, void* d_ws, size_t ws_size,
                              hipStream_t stream) {
    const int*   y_true = (const int*)d_in[0];    // [B, L] int32
    const float* y_pred = (const float*)d_in[1];  // [B, T, V] float32
    float* focal_ws = (float*)d_ws;               // [B]

    fused_kernel<<<Bb, 1024, 0, stream>>>(y_true, y_pred, focal_ws);
    finalize_kernel<<<1, 256, 0, stream>>>(focal_ws, (float*)d_out);
}